// Round 10
// baseline (519.678 us; speedup 1.0000x reference)
//
#include <hip/hip_runtime.h>

// Biaffine: B=8, L=512, H=768, O=12
// inputs (B,L,H) fp32 ; weight1 (H,O,H) fp32 ; weight2 (2H+1,O) fp32 ;
// mask (B,L) int32 ; out (B,O,L,L) FLOAT32.
//
// R8 = 281 us (gemm1 79 us, MfmaUtil 15%, VGPR 104, latency-bound on the
// GLDS->vmcnt(0)->barrier chain). R9 dbuf regressed (VGPR 224, occ 11%).
// R10: R8 structure + REGISTER-prefetch pipeline (load tile k+1 into VGPRs
// during compute of k; ds_write at top of k+1 -> vmcnt wait is off the
// critical path, no extra LDS, modest VGPR) + gemm1 epilogue repack via LDS
// (64 byte-stores/thread -> 4 dwordx4 stores/thread).

#define NEGV 1e12f

typedef __attribute__((ext_vector_type(4))) float f32x4;
typedef __attribute__((ext_vector_type(8))) int   i32x8;

// ---- float -> OCP e4m3fn (flush |v|<2^-6 to 0, round-half-up, sat 448) ----
__device__ __forceinline__ unsigned char f2fp8(float f) {
    union { float f; unsigned u; } c; c.f = f;
    unsigned s = (c.u >> 24) & 0x80;
    unsigned a = c.u & 0x7FFFFFFF;
    if (a < 0x3C800000u) return (unsigned char)s;        // |v| < 2^-6 -> 0
    a += 0x80000;                                        // round at bit 20
    int e = (int)(a >> 23) - 127;
    unsigned m = (a >> 20) & 7;
    if (e > 8 || (e == 8 && m == 7)) return (unsigned char)(s | 0x7E);  // sat 448
    return (unsigned char)(s | ((e + 7) << 3) | m);
}

// ---------------- cast inputs fp32 -> fp8 ----------------
__global__ void cast_a_kernel(const float* __restrict__ in,
                              unsigned char* __restrict__ out, int n4) {
    int i = blockIdx.x * blockDim.x + threadIdx.x;
    if (i < n4) {
        float4 v = ((const float4*)in)[i];
        uchar4 o;
        o.x = f2fp8(v.x); o.y = f2fp8(v.y); o.z = f2fp8(v.z); o.w = f2fp8(v.w);
        ((uchar4*)out)[i] = o;
    }
}

// ---- transpose weight1 (768 x 9216) -> W1T (9216 x 768) fp8, pre-scaled x16 ----
__global__ void transpose_w1_kernel(const float* __restrict__ w1,
                                    unsigned char* __restrict__ w1t) {
    __shared__ float t[64][65];
    const int n0 = blockIdx.x * 64;    // 9216/64 = 144
    const int i0 = blockIdx.y * 64;    // 768/64  = 12
    const int c  = threadIdx.x & 63;
    const int r4 = threadIdx.x >> 6;   // 0..3
    #pragma unroll
    for (int p = 0; p < 16; ++p) {
        int il = p * 4 + r4;
        t[il][c] = w1[(size_t)(i0 + il) * 9216 + n0 + c];
    }
    __syncthreads();
    #pragma unroll
    for (int p = 0; p < 16; ++p) {
        int nl = p * 4 + r4;
        w1t[(size_t)(n0 + nl) * 768 + i0 + c] = f2fp8(t[c][nl] * 16.0f);
    }
}

// ---------------- lin_i / lin_j (inputs @ wa, inputs @ wb), fp32 ----------------
__global__ void lin_kernel(const float* __restrict__ x, const float* __restrict__ w2,
                           float* __restrict__ li, float* __restrict__ lj) {
    int t = blockIdx.x * blockDim.x + threadIdx.x;
    if (t >= 4096 * 12) return;
    int bx = t / 12, o = t % 12;
    const float4* xp4 = (const float4*)(x + (size_t)bx * 768);
    float sa = 0.f, sb = 0.f;
    for (int h4 = 0; h4 < 192; ++h4) {
        float4 v = xp4[h4];
        int h = h4 * 4;
        sa += v.x * w2[h * 12 + o]        + v.y * w2[(h + 1) * 12 + o]
            + v.z * w2[(h + 2) * 12 + o]  + v.w * w2[(h + 3) * 12 + o];
        sb += v.x * w2[(768 + h) * 12 + o]       + v.y * w2[(769 + h) * 12 + o]
            + v.z * w2[(770 + h) * 12 + o]       + v.w * w2[(771 + h) * 12 + o];
    }
    li[t] = sa; lj[t] = sb;
}

// ------- 128x128xBK=128 fp8 bt-GEMM, register-prefetch pipeline -------
// A: 128 rows, pitch lda (bytes), K-contiguous. B: 128 rows (N dim), pitch ldb.
// LDS: row r = 128 B = 8 slots of 16 B; slot s holds global chunk s^(r&7).
// Read side: slot ((2kg+j)^(fr&7)) of row ra (ra&7==fr&7) => true k-order.
__device__ __forceinline__ void gemm128_fp8_rp(
    const unsigned char* __restrict__ A, int lda,
    const unsigned char* __restrict__ B, int ldb,
    char* As, char* Bs, f32x4 (&acc)[4][4], int sA, int sB) {
    const int tid  = threadIdx.x;
    const int lane = tid & 63;
    const int wave = tid >> 6;
    // staging geometry: chunk cc = tid + 256*t; row=cc>>3 (=row0+32t), slot=cc&7.
    // g = slot^(row&7) is t-invariant; src(t) = src0 + 32*t*pitch.
    const int row0 = tid >> 3;
    const int g0   = (tid & 7) ^ (row0 & 7);
    const unsigned char* aS0 = A + (size_t)row0 * lda + g0 * 16;
    const unsigned char* bS0 = B + (size_t)row0 * ldb + g0 * 16;
    const int dst0 = tid * 16;                    // + 4096*t
    // fragment read bases (slot xor value = fr&7, invariant across mi/ni)
    const int wm = (wave >> 1) * 64;
    const int wn = (wave & 1) * 64;
    const int fr = lane & 15;
    const int kg = lane >> 4;
    const int baseA0 = (wm + fr) * 128 + (((2 * kg)    ) ^ (fr & 7)) * 16;
    const int baseA1 = (wm + fr) * 128 + (((2 * kg) + 1) ^ (fr & 7)) * 16;
    const int baseB0 = (wn + fr) * 128 + (((2 * kg)    ) ^ (fr & 7)) * 16;
    const int baseB1 = (wn + fr) * 128 + (((2 * kg) + 1) ^ (fr & 7)) * 16;

    uint4 pa[4], pb[4];
    #pragma unroll
    for (int t = 0; t < 4; ++t) {
        pa[t] = *(const uint4*)(aS0 + (size_t)(32 * t) * lda);
        pb[t] = *(const uint4*)(bS0 + (size_t)(32 * t) * ldb);
    }
    #pragma unroll
    for (int it = 0; it < 6; ++it) {
        __syncthreads();               // prior iteration's ds_reads complete
        #pragma unroll
        for (int t = 0; t < 4; ++t) {
            *(uint4*)(As + dst0 + 4096 * t) = pa[t];
            *(uint4*)(Bs + dst0 + 4096 * t) = pb[t];
        }
        if (it < 5) {                  // prefetch tile it+1 into registers;
            const int kk = (it + 1) * 128;   // consumed only after next barrier
            #pragma unroll
            for (int t = 0; t < 4; ++t) {
                pa[t] = *(const uint4*)(aS0 + (size_t)(32 * t) * lda + kk);
                pb[t] = *(const uint4*)(bS0 + (size_t)(32 * t) * ldb + kk);
            }
        }
        __syncthreads();               // staged tile visible
        i32x8 bf[4];
        #pragma unroll
        for (int ni = 0; ni < 4; ++ni) {
            const uint4 lo = *(const uint4*)(Bs + baseB0 + 2048 * ni);
            const uint4 hi = *(const uint4*)(Bs + baseB1 + 2048 * ni);
            bf[ni][0] = lo.x; bf[ni][1] = lo.y; bf[ni][2] = lo.z; bf[ni][3] = lo.w;
            bf[ni][4] = hi.x; bf[ni][5] = hi.y; bf[ni][6] = hi.z; bf[ni][7] = hi.w;
        }
        #pragma unroll
        for (int mi = 0; mi < 4; ++mi) {
            const uint4 lo = *(const uint4*)(As + baseA0 + 2048 * mi);
            const uint4 hi = *(const uint4*)(As + baseA1 + 2048 * mi);
            i32x8 af;
            af[0] = lo.x; af[1] = lo.y; af[2] = lo.z; af[3] = lo.w;
            af[4] = hi.x; af[5] = hi.y; af[6] = hi.z; af[7] = hi.w;
            #pragma unroll
            for (int ni = 0; ni < 4; ++ni)
                acc[mi][ni] = __builtin_amdgcn_mfma_scale_f32_16x16x128_f8f6f4(
                    af, bf[ni], acc[mi][ni], 0, 0, 0, sA, 0, sB);
        }
    }
}

// ---- GEMM1: U[bx, n] = A(4096x768) x W1T(9216x768)^T, fp8 out pitch 9216 ----
__global__ __launch_bounds__(256) void gemm1_kernel(
    const unsigned char* __restrict__ A8,
    const unsigned char* __restrict__ W8,
    unsigned char* __restrict__ U) {
    __shared__ __align__(16) char As[128 * 128];
    __shared__ __align__(16) char Bs[128 * 128];
    const int m0 = blockIdx.x * 128;  // 32 tiles
    const int n0 = blockIdx.y * 128;  // 72 tiles
    f32x4 acc[4][4] = {};
    gemm128_fp8_rp(A8 + (size_t)m0 * 768, 768, W8 + (size_t)n0 * 768, 768,
                   As, Bs, acc, 0x7F7F7F7F, 0x7B7B7B7B);  // W x16 -> sB=2^-4
    const int tid  = threadIdx.x;
    const int lane = tid & 63;
    const int wave = tid >> 6;
    const int wm = (wave >> 1) * 64, wn = (wave & 1) * 64;
    const int rl = (lane >> 4) * 4, cl = lane & 15;
    __syncthreads();                   // K-loop LDS reads done; reuse As as C-tile
    #pragma unroll
    for (int mi = 0; mi < 4; ++mi)
        #pragma unroll
        for (int ni = 0; ni < 4; ++ni)
            #pragma unroll
            for (int r = 0; r < 4; ++r)
                As[(wm + mi * 16 + rl + r) * 128 + wn + ni * 16 + cl] =
                    (char)f2fp8(acc[mi][ni][r]);
    __syncthreads();
    #pragma unroll
    for (int t = 0; t < 4; ++t) {
        const int cc = tid + 256 * t;
        const int row = cc >> 3, s = cc & 7;
        *(uint4*)(U + (size_t)(m0 + row) * 9216 + n0 + s * 16) =
            *(const uint4*)(As + row * 128 + s * 16);
    }
}

// ---- GEMM2 + epilogue: out[b,o,x,y] (fp32), z = b*12+o ----
__global__ __launch_bounds__(256) void gemm2_kernel(
    const unsigned char* __restrict__ U,
    const unsigned char* __restrict__ A8,
    const float* __restrict__ li,
    const float* __restrict__ lj,
    const float* __restrict__ w2,
    const int* __restrict__ mask,
    float* __restrict__ out) {
    __shared__ __align__(16) char As[128 * 128];
    __shared__ __align__(16) char Bs[128 * 128];
    const int bo = blockIdx.z;           // 0..95
    const int b = bo / 12, o = bo % 12;
    const int x0 = blockIdx.x * 128;
    const int y0 = blockIdx.y * 128;
    f32x4 acc[4][4] = {};
    gemm128_fp8_rp(U + (size_t)(b * 512 + x0) * 9216 + (size_t)o * 768, 9216,
                   A8 + (size_t)(b * 512 + y0) * 768, 768,
                   As, Bs, acc, 0x7F7F7F7F, 0x7F7F7F7F);
    const float bias = w2[1536 * 12 + o];
    float* outp = out + ((size_t)bo) * 512 * 512;
    const int lane = threadIdx.x & 63;
    const int wave = threadIdx.x >> 6;
    const int wm = (wave >> 1) * 64, wn = (wave & 1) * 64;
    const int rl = (lane >> 4) * 4, cl = lane & 15;
    #pragma unroll
    for (int mi = 0; mi < 4; ++mi) {
        const int xb = x0 + wm + mi * 16 + rl;
        float liv[4]; int mr[4];
        #pragma unroll
        for (int r = 0; r < 4; ++r) {
            liv[r] = li[(size_t)(b * 512 + xb + r) * 12 + o];
            mr[r]  = mask[b * 512 + xb + r];
        }
        #pragma unroll
        for (int ni = 0; ni < 4; ++ni) {
            const int y = y0 + wn + ni * 16 + cl;
            const float ljv = lj[(size_t)(b * 512 + y) * 12 + o];
            const int mc = mask[b * 512 + y];
            #pragma unroll
            for (int r = 0; r < 4; ++r) {
                float v = acc[mi][ni][r] + liv[r] + ljv + bias;
                if (!(mr[r] & mc)) v = -NEGV;      // row or col masked -> -1e12
                if (xb + r > y)    v -= NEGV;      // strict lower tri -> extra -1e12
                outp[(size_t)(xb + r) * 512 + y] = v;   // FP32 store
            }
        }
    }
}

extern "C" void kernel_launch(void* const* d_in, const int* in_sizes, int n_in,
                              void* d_out, int out_size, void* d_ws, size_t ws_size,
                              hipStream_t stream) {
    const float* inputs = (const float*)d_in[0];
    const float* w1     = (const float*)d_in[1];
    const float* w2     = (const float*)d_in[2];
    const int*   mask   = (const int*)d_in[3];
    float* outp = (float*)d_out;

    // workspace layout (46.1 MB used; ws_size = 384 MiB per R6 fill counters)
    char* ws = (char*)d_ws;
    float* li         = (float*)(ws + 0);                  //    196,608 B
    float* lj         = (float*)(ws + 196608);             //    196,608 B
    unsigned char* A8 = (unsigned char*)(ws + 393216);     //  3,145,728 B
    unsigned char* W8 = (unsigned char*)(ws + 3538944);    //  7,077,888 B
    unsigned char* U8 = (unsigned char*)(ws + 10616832);   // 37,748,736 B -> ends 48,365,568

    cast_a_kernel<<<3072, 256, 0, stream>>>(inputs, A8, 786432);
    lin_kernel<<<192, 256, 0, stream>>>(inputs, w2, li, lj);
    transpose_w1_kernel<<<dim3(144, 12), 256, 0, stream>>>(w1, W8);
    gemm1_kernel<<<dim3(32, 72), 256, 0, stream>>>(A8, W8, U8);
    gemm2_kernel<<<dim3(4, 4, 96), 256, 0, stream>>>(U8, A8, li, lj, w2, mask, outp);
}